// Round 1
// baseline (1046.628 us; speedup 1.0000x reference)
//
#include <hip/hip_runtime.h>
#include <cstddef>

#define SCALE_WEIGHT 0.70710678118654752440f

static constexpr int B_ = 8, C_ = 512, T_ = 2048, S_ = 2048;
static constexpr size_t BCT_ = (size_t)B_ * C_ * T_;   // context_output elements
static constexpr size_t BTS_ = (size_t)B_ * T_ * S_;   // attn elements

// ---------------------------------------------------------------------------
// K1: target[b][o][t] = (base[b][o][t] + bias[o] + sum_c W[o][c]*x[b][c][t]) * SCALE
// GEMM per batch: M=C (o), N=T (t), K=C (c). BM=BN=128, BK=8, 256 thr, 8x8/thr.
// A = W[m][k] (m-major -> transpose on LDS store). B = x[k][n] (direct).
// ---------------------------------------------------------------------------
__global__ __launch_bounds__(256) void k1_target_kernel(
    const float* __restrict__ W, const float* __restrict__ x,
    const float* __restrict__ base, const float* __restrict__ bias,
    float* __restrict__ tgt)
{
    __shared__ float As[8][132];
    __shared__ float Bs[8][132];
    const int tid = threadIdx.x;
    const int b  = blockIdx.z;
    const int m0 = blockIdx.y * 128;
    const int n0 = blockIdx.x * 128;
    const int tx = tid & 15, ty = tid >> 4;
    const int ty4 = ty * 4, tx4 = tx * 4;
    const int ar = tid >> 1, aq = tid & 1;         // A transpose-load: row, quad
    const int bk = tid >> 5, bn = (tid & 31) * 4;  // B direct-load

    const float* xb = x + (size_t)b * C_ * T_;

    float acc[8][8];
    #pragma unroll
    for (int i = 0; i < 8; ++i)
        #pragma unroll
        for (int j = 0; j < 8; ++j) acc[i][j] = 0.f;

    for (int k0 = 0; k0 < C_; k0 += 8) {
        float4 av = *(const float4*)&W[(size_t)(m0 + ar) * C_ + k0 + aq * 4];
        float4 bv = *(const float4*)&xb[(size_t)(k0 + bk) * T_ + n0 + bn];
        __syncthreads();
        As[aq * 4 + 0][ar] = av.x;
        As[aq * 4 + 1][ar] = av.y;
        As[aq * 4 + 2][ar] = av.z;
        As[aq * 4 + 3][ar] = av.w;
        *(float4*)&Bs[bk][bn] = bv;
        __syncthreads();
        #pragma unroll
        for (int k = 0; k < 8; ++k) {
            float4 a0 = *(const float4*)&As[k][ty4];
            float4 a1 = *(const float4*)&As[k][ty4 + 64];
            float4 b0 = *(const float4*)&Bs[k][tx4];
            float4 b1 = *(const float4*)&Bs[k][tx4 + 64];
            float avv[8] = {a0.x, a0.y, a0.z, a0.w, a1.x, a1.y, a1.z, a1.w};
            float bvv[8] = {b0.x, b0.y, b0.z, b0.w, b1.x, b1.y, b1.z, b1.w};
            #pragma unroll
            for (int i = 0; i < 8; ++i)
                #pragma unroll
                for (int j = 0; j < 8; ++j)
                    acc[i][j] += avv[i] * bvv[j];
        }
    }

    #pragma unroll
    for (int i = 0; i < 8; ++i) {
        const int m = m0 + ((i & 4) ? 64 : 0) + ty4 + (i & 3);
        const float bm = bias[m];
        const float* baserow = base + ((size_t)b * C_ + m) * T_;
        float* trow = tgt + ((size_t)b * C_ + m) * T_;
        #pragma unroll
        for (int jh = 0; jh < 2; ++jh) {
            const int n = n0 + jh * 64 + tx4;
            float4 bs = *(const float4*)&baserow[n];
            float4 r;
            r.x = (bs.x + bm + acc[i][jh * 4 + 0]) * SCALE_WEIGHT;
            r.y = (bs.y + bm + acc[i][jh * 4 + 1]) * SCALE_WEIGHT;
            r.z = (bs.z + bm + acc[i][jh * 4 + 2]) * SCALE_WEIGHT;
            r.w = (bs.w + bm + acc[i][jh * 4 + 3]) * SCALE_WEIGHT;
            *(float4*)&trow[n] = r;
        }
    }
}

// ---------------------------------------------------------------------------
// K2: logits[b][t][s] = sum_c target[b][c][t] * top[b][c][s]
// GEMM per batch: M=T, N=S, K=C. Both operands K-major -> direct LDS stores.
// ---------------------------------------------------------------------------
__global__ __launch_bounds__(256) void k2_logits_kernel(
    const float* __restrict__ tgt, const float* __restrict__ top,
    float* __restrict__ logits)
{
    __shared__ float As[8][132];
    __shared__ float Bs[8][132];
    const int tid = threadIdx.x;
    const int b  = blockIdx.z;
    const int m0 = blockIdx.y * 128;
    const int n0 = blockIdx.x * 128;
    const int tx = tid & 15, ty = tid >> 4;
    const int ty4 = ty * 4, tx4 = tx * 4;
    const int lk = tid >> 5, lc = (tid & 31) * 4;  // both loads direct

    const float* tb = tgt + (size_t)b * C_ * T_;
    const float* eb = top + (size_t)b * C_ * S_;

    float acc[8][8];
    #pragma unroll
    for (int i = 0; i < 8; ++i)
        #pragma unroll
        for (int j = 0; j < 8; ++j) acc[i][j] = 0.f;

    for (int k0 = 0; k0 < C_; k0 += 8) {
        float4 av = *(const float4*)&tb[(size_t)(k0 + lk) * T_ + m0 + lc];
        float4 bv = *(const float4*)&eb[(size_t)(k0 + lk) * S_ + n0 + lc];
        __syncthreads();
        *(float4*)&As[lk][lc] = av;
        *(float4*)&Bs[lk][lc] = bv;
        __syncthreads();
        #pragma unroll
        for (int k = 0; k < 8; ++k) {
            float4 a0 = *(const float4*)&As[k][ty4];
            float4 a1 = *(const float4*)&As[k][ty4 + 64];
            float4 b0 = *(const float4*)&Bs[k][tx4];
            float4 b1 = *(const float4*)&Bs[k][tx4 + 64];
            float avv[8] = {a0.x, a0.y, a0.z, a0.w, a1.x, a1.y, a1.z, a1.w};
            float bvv[8] = {b0.x, b0.y, b0.z, b0.w, b1.x, b1.y, b1.z, b1.w};
            #pragma unroll
            for (int i = 0; i < 8; ++i)
                #pragma unroll
                for (int j = 0; j < 8; ++j)
                    acc[i][j] += avv[i] * bvv[j];
        }
    }

    #pragma unroll
    for (int i = 0; i < 8; ++i) {
        const int m = m0 + ((i & 4) ? 64 : 0) + ty4 + (i & 3);
        float* lrow = logits + ((size_t)b * T_ + m) * S_;
        #pragma unroll
        for (int jh = 0; jh < 2; ++jh) {
            const int n = n0 + jh * 64 + tx4;
            float4 r;
            r.x = acc[i][jh * 4 + 0];
            r.y = acc[i][jh * 4 + 1];
            r.z = acc[i][jh * 4 + 2];
            r.w = acc[i][jh * 4 + 3];
            *(float4*)&lrow[n] = r;
        }
    }
}

// ---------------------------------------------------------------------------
// K3: in-place row softmax over the last (S) axis. One block per (b,t) row.
// ---------------------------------------------------------------------------
__global__ __launch_bounds__(256) void k3_softmax_kernel(float* __restrict__ logits)
{
    float* p = logits + (size_t)blockIdx.x * S_;
    const int tid = threadIdx.x;
    float4 v0 = *(const float4*)&p[tid * 4];
    float4 v1 = *(const float4*)&p[tid * 4 + 1024];

    float mx = fmaxf(fmaxf(fmaxf(v0.x, v0.y), fmaxf(v0.z, v0.w)),
                     fmaxf(fmaxf(v1.x, v1.y), fmaxf(v1.z, v1.w)));
    #pragma unroll
    for (int off = 32; off; off >>= 1)
        mx = fmaxf(mx, __shfl_xor(mx, off));

    __shared__ float sm[4];
    __shared__ float ss[4];
    const int wid = tid >> 6, lane = tid & 63;
    if (lane == 0) sm[wid] = mx;
    __syncthreads();
    const float rmax = fmaxf(fmaxf(sm[0], sm[1]), fmaxf(sm[2], sm[3]));

    float e[8];
    e[0] = expf(v0.x - rmax); e[1] = expf(v0.y - rmax);
    e[2] = expf(v0.z - rmax); e[3] = expf(v0.w - rmax);
    e[4] = expf(v1.x - rmax); e[5] = expf(v1.y - rmax);
    e[6] = expf(v1.z - rmax); e[7] = expf(v1.w - rmax);

    float sum = 0.f;
    #pragma unroll
    for (int i = 0; i < 8; ++i) sum += e[i];
    #pragma unroll
    for (int off = 32; off; off >>= 1)
        sum += __shfl_xor(sum, off);
    if (lane == 0) ss[wid] = sum;
    __syncthreads();
    const float inv = 1.f / (ss[0] + ss[1] + ss[2] + ss[3]);

    float4 r0, r1;
    r0.x = e[0] * inv; r0.y = e[1] * inv; r0.z = e[2] * inv; r0.w = e[3] * inv;
    r1.x = e[4] * inv; r1.y = e[5] * inv; r1.z = e[6] * inv; r1.w = e[7] * inv;
    *(float4*)&p[tid * 4] = r0;
    *(float4*)&p[tid * 4 + 1024] = r1;
}

// ---------------------------------------------------------------------------
// K4: context[b][c][t] = sum_s attn[b][t][s] * comb[b][c][s]
// GEMM per batch: M=C (c), N=T (t), K=S. Both operands M/N-major (k-contig)
// -> transpose on LDS store for both.
// ---------------------------------------------------------------------------
__global__ __launch_bounds__(256) void k4_ctx_kernel(
    const float* __restrict__ attn, const float* __restrict__ comb,
    float* __restrict__ out0)
{
    __shared__ float As[8][132];
    __shared__ float Bs[8][132];
    const int tid = threadIdx.x;
    const int b  = blockIdx.z;
    const int m0 = blockIdx.y * 128;   // c
    const int n0 = blockIdx.x * 128;   // t
    const int tx = tid & 15, ty = tid >> 4;
    const int ty4 = ty * 4, tx4 = tx * 4;
    const int ar = tid >> 1, aq = tid & 1;

    const float* cb = comb + (size_t)b * C_ * S_;
    const float* ab = attn + (size_t)b * T_ * S_;

    float acc[8][8];
    #pragma unroll
    for (int i = 0; i < 8; ++i)
        #pragma unroll
        for (int j = 0; j < 8; ++j) acc[i][j] = 0.f;

    for (int k0 = 0; k0 < S_; k0 += 8) {
        float4 av = *(const float4*)&cb[(size_t)(m0 + ar) * S_ + k0 + aq * 4];
        float4 bv = *(const float4*)&ab[(size_t)(n0 + ar) * S_ + k0 + aq * 4];
        __syncthreads();
        As[aq * 4 + 0][ar] = av.x;
        As[aq * 4 + 1][ar] = av.y;
        As[aq * 4 + 2][ar] = av.z;
        As[aq * 4 + 3][ar] = av.w;
        Bs[aq * 4 + 0][ar] = bv.x;
        Bs[aq * 4 + 1][ar] = bv.y;
        Bs[aq * 4 + 2][ar] = bv.z;
        Bs[aq * 4 + 3][ar] = bv.w;
        __syncthreads();
        #pragma unroll
        for (int k = 0; k < 8; ++k) {
            float4 a0 = *(const float4*)&As[k][ty4];
            float4 a1 = *(const float4*)&As[k][ty4 + 64];
            float4 b0 = *(const float4*)&Bs[k][tx4];
            float4 b1 = *(const float4*)&Bs[k][tx4 + 64];
            float avv[8] = {a0.x, a0.y, a0.z, a0.w, a1.x, a1.y, a1.z, a1.w};
            float bvv[8] = {b0.x, b0.y, b0.z, b0.w, b1.x, b1.y, b1.z, b1.w};
            #pragma unroll
            for (int i = 0; i < 8; ++i)
                #pragma unroll
                for (int j = 0; j < 8; ++j)
                    acc[i][j] += avv[i] * bvv[j];
        }
    }

    #pragma unroll
    for (int i = 0; i < 8; ++i) {
        const int m = m0 + ((i & 4) ? 64 : 0) + ty4 + (i & 3);   // c
        float* orow = out0 + ((size_t)b * C_ + m) * T_;
        #pragma unroll
        for (int jh = 0; jh < 2; ++jh) {
            const int n = n0 + jh * 64 + tx4;                     // t
            float4 r;
            r.x = acc[i][jh * 4 + 0];
            r.y = acc[i][jh * 4 + 1];
            r.z = acc[i][jh * 4 + 2];
            r.w = acc[i][jh * 4 + 3];
            *(float4*)&orow[n] = r;
        }
    }
}

extern "C" void kernel_launch(void* const* d_in, const int* in_sizes, int n_in,
                              void* d_out, int out_size, void* d_ws, size_t ws_size,
                              hipStream_t stream) {
    const float* base = (const float*)d_in[0];  // [B,C,T,1]
    const float* x    = (const float*)d_in[1];  // [B,C,T,1]
    const float* top  = (const float*)d_in[2];  // [B,C,S]
    const float* comb = (const float*)d_in[3];  // [B,C,S]
    const float* W    = (const float*)d_in[4];  // [C,C]
    const float* bias = (const float*)d_in[5];  // [C]

    float* out  = (float*)d_out;
    float* ctx  = out;          // [B,C,T] final context output
    float* attn = out + BCT_;   // [B,T,S] attn output (holds logits pre-softmax)
    // Stage `target` in the context region of d_out: it is fully consumed by K2
    // before K4 overwrites the region with the real context output. Every byte
    // of d_out is rewritten each call -> deterministic under graph replay.
    float* tgt = ctx;

    // K1: target = (base + W @ x + b) * SCALE           [B,C,T]
    k1_target_kernel<<<dim3(T_ / 128, C_ / 128, B_), 256, 0, stream>>>(W, x, base, bias, tgt);
    // K2: logits = target^T @ top                        [B,T,S]
    k2_logits_kernel<<<dim3(S_ / 128, T_ / 128, B_), 256, 0, stream>>>(tgt, top, attn);
    // K3: attn = softmax(logits, axis=s) in-place
    k3_softmax_kernel<<<dim3(B_ * T_), 256, 0, stream>>>(attn);
    // K4: context = attn @ comb^T (written transposed)   [B,C,T]
    k4_ctx_kernel<<<dim3(T_ / 128, C_ / 128, B_), 256, 0, stream>>>(attn, comb, ctx);
}

// Round 2
// 246.746 us; speedup vs baseline: 4.2417x; 4.2417x over previous
//
#include <hip/hip_runtime.h>
#include <cstddef>
#include <cstdint>

#define SCALE_WEIGHT 0.70710678118654752440f

static constexpr int B_ = 8, C_ = 512, T_ = 2048, S_ = 2048;
static constexpr size_t BCT_ = (size_t)B_ * C_ * T_;   // 8.4M  (ctx region elems)
static constexpr size_t BTS_ = (size_t)B_ * T_ * S_;   // 33.5M (attn region elems)

typedef _Float16 half_t;
typedef half_t half8  __attribute__((ext_vector_type(8)));
typedef half_t half4v __attribute__((ext_vector_type(4)));
typedef float  floatx4 __attribute__((ext_vector_type(4)));

// async global->LDS, 16B per lane. LDS dest = wave-uniform base + lane*16.
__device__ __forceinline__ void gload_lds16(const void* g, void* l) {
    __builtin_amdgcn_global_load_lds(
        (const __attribute__((address_space(1))) void*)g,
        (__attribute__((address_space(3))) void*)l, 16, 0, 0);
}

// ---------------------------------------------------------------------------
// transpose+convert: in [b][R][Cc] f32 -> out [b][Cc][R] f16
// ---------------------------------------------------------------------------
__global__ __launch_bounds__(256) void transpose_cvt_kernel(
    const float* __restrict__ in, half_t* __restrict__ out, int R, int Cc)
{
    __shared__ float tile[32][33];
    const int b  = blockIdx.z;
    const int r0 = blockIdx.y * 32, c0 = blockIdx.x * 32;
    const float* ib = in + (size_t)b * R * Cc;
    half_t* ob = out + (size_t)b * R * Cc;
    const int tx = threadIdx.x & 31, ty = threadIdx.x >> 5;
    #pragma unroll
    for (int i = 0; i < 4; ++i)
        tile[ty + i * 8][tx] = ib[(size_t)(r0 + ty + i * 8) * Cc + c0 + tx];
    __syncthreads();
    #pragma unroll
    for (int i = 0; i < 4; ++i)
        ob[(size_t)(c0 + ty + i * 8) * R + r0 + tx] = (half_t)tile[tx][ty + i * 8];
}

// ---------------------------------------------------------------------------
// plain convert f32 -> f16 (same layout), float4-granular
// ---------------------------------------------------------------------------
__global__ __launch_bounds__(256) void cvt_f32_f16_kernel(
    const float* __restrict__ in, half_t* __restrict__ out, int n4)
{
    const int stride = gridDim.x * blockDim.x;
    for (int i = blockIdx.x * blockDim.x + threadIdx.x; i < n4; i += stride) {
        float4 v = ((const float4*)in)[i];
        half4v h = {(half_t)v.x, (half_t)v.y, (half_t)v.z, (half_t)v.w};
        ((half4v*)out)[i] = h;
    }
}

// ---------------------------------------------------------------------------
// MFMA fp16 GEMM, m97 structure: 128x128 tile, 4 waves (64x64 each), BK=32,
// global_load_lds(16B) staging, linear LDS [128][32] halves with kg-XOR
// swizzle applied on BOTH the staging global source and the ds_read address.
// A: [M][K] f16 k-contig.  B: [N][K] f16 k-contig.  C: [M][N].
// EPI 0: f32 store.  EPI 1 (K1): f16 store of (acc + bias[n] + base[b][n][m])*SCALE.
// ---------------------------------------------------------------------------
template<int EPI>
__global__ __launch_bounds__(256) void gemm_f16_kernel(
    const half_t* __restrict__ A, const half_t* __restrict__ Bm,
    float* __restrict__ Cout, half_t* __restrict__ CoutH,
    const float* __restrict__ base, const float* __restrict__ bias,
    int M, int N, int K, size_t sA, size_t sB, size_t sC)
{
    __shared__ __align__(128) half_t As[128 * 32];
    __shared__ __align__(128) half_t Bs[128 * 32];

    const int tid  = threadIdx.x;
    const int lane = tid & 63, w = tid >> 6;
    const int wr = w >> 1, wc = w & 1;
    const int b  = blockIdx.z;
    const int m0 = blockIdx.y * 128, n0 = blockIdx.x * 128;

    const half_t* Ab = A  + (size_t)b * sA;
    const half_t* Bb = Bm + (size_t)b * sB;

    // ---- staging addresses (2 chunks of 1KB per wave per operand) ----
    const int w2  = w * 2;
    const int mR0 = w2 * 16 + (lane >> 2);       // LDS row of chunk 0
    const int mR1 = mR0 + 16;                    // LDS row of chunk 1
    const int kgd = lane & 3;                    // dest kg slot
    const int kgs0 = kgd ^ ((mR0 >> 1) & 3);     // swizzled source kg
    const int kgs1 = kgd ^ ((mR1 >> 1) & 3);
    const half_t* aSrc0 = Ab + (size_t)(m0 + mR0) * K + kgs0 * 8;
    const half_t* aSrc1 = Ab + (size_t)(m0 + mR1) * K + kgs1 * 8;
    const half_t* bSrc0 = Bb + (size_t)(n0 + mR0) * K + kgs0 * 8;
    const half_t* bSrc1 = Bb + (size_t)(n0 + mR1) * K + kgs1 * 8;
    char* AsB = (char*)As;
    char* BsB = (char*)Bs;
    char* dA0 = AsB + (w2 + 0) * 1024;  // wave-uniform LDS bases
    char* dA1 = AsB + (w2 + 1) * 1024;
    char* dB0 = BsB + (w2 + 0) * 1024;
    char* dB1 = BsB + (w2 + 1) * 1024;

    // ---- fragment ds_read byte offsets (constant across K-steps) ----
    const int fr = lane & 15, kg = lane >> 4;
    int aoff[4], boff[4];
    #pragma unroll
    for (int mi = 0; mi < 4; ++mi) {
        int m = wr * 64 + mi * 16 + fr;
        aoff[mi] = m * 64 + ((kg ^ ((m >> 1) & 3)) << 4);
    }
    #pragma unroll
    for (int nj = 0; nj < 4; ++nj) {
        int n = wc * 64 + nj * 16 + fr;
        boff[nj] = n * 64 + ((kg ^ ((n >> 1) & 3)) << 4);
    }

    floatx4 acc[4][4];
    #pragma unroll
    for (int mi = 0; mi < 4; ++mi)
        #pragma unroll
        for (int nj = 0; nj < 4; ++nj)
            acc[mi][nj] = (floatx4){0.f, 0.f, 0.f, 0.f};

    for (int k0 = 0; k0 < K; k0 += 32) {
        __syncthreads();                 // previous compute done reading LDS
        gload_lds16(aSrc0 + k0, dA0);
        gload_lds16(aSrc1 + k0, dA1);
        gload_lds16(bSrc0 + k0, dB0);
        gload_lds16(bSrc1 + k0, dB1);
        __syncthreads();                 // compiler drains vmcnt before barrier

        half8 af[4], bf[4];
        #pragma unroll
        for (int mi = 0; mi < 4; ++mi) af[mi] = *(const half8*)(AsB + aoff[mi]);
        #pragma unroll
        for (int nj = 0; nj < 4; ++nj) bf[nj] = *(const half8*)(BsB + boff[nj]);
        #pragma unroll
        for (int mi = 0; mi < 4; ++mi)
            #pragma unroll
            for (int nj = 0; nj < 4; ++nj)
                acc[mi][nj] = __builtin_amdgcn_mfma_f32_16x16x32_f16(
                    af[mi], bf[nj], acc[mi][nj], 0, 0, 0);
    }

    if constexpr (EPI == 0) {
        float* Cb = Cout + (size_t)b * sC;
        #pragma unroll
        for (int mi = 0; mi < 4; ++mi) {
            const int row = m0 + wr * 64 + mi * 16 + (lane >> 4) * 4;
            #pragma unroll
            for (int nj = 0; nj < 4; ++nj) {
                const int col = n0 + wc * 64 + nj * 16 + (lane & 15);
                #pragma unroll
                for (int r = 0; r < 4; ++r)
                    Cb[(size_t)(row + r) * N + col] = acc[mi][nj][r];
            }
        }
    } else {
        half_t* Cb = CoutH + (size_t)b * sC;
        #pragma unroll
        for (int nj = 0; nj < 4; ++nj) {
            const int col = n0 + wc * 64 + nj * 16 + (lane & 15);
            const float bn = bias[col];
            const float* bp = base + ((size_t)b * N + col) * (size_t)M;
            #pragma unroll
            for (int mi = 0; mi < 4; ++mi) {
                const int row = m0 + wr * 64 + mi * 16 + (lane >> 4) * 4;
                #pragma unroll
                for (int r = 0; r < 4; ++r) {
                    float v = (acc[mi][nj][r] + bn + bp[row + r]) * SCALE_WEIGHT;
                    Cb[(size_t)(row + r) * N + col] = (half_t)v;
                }
            }
        }
    }
}

// ---------------------------------------------------------------------------
// row softmax over S, in-place f32 + fp16 copy for the K4 MFMA operand
// ---------------------------------------------------------------------------
__global__ __launch_bounds__(256) void k3_softmax_kernel(
    float* __restrict__ logits, half_t* __restrict__ attnh)
{
    float* p = logits + (size_t)blockIdx.x * S_;
    half4v* ph = (half4v*)(attnh + (size_t)blockIdx.x * S_);
    const int tid = threadIdx.x;
    float4 v0 = *(const float4*)&p[tid * 4];
    float4 v1 = *(const float4*)&p[tid * 4 + 1024];

    float mx = fmaxf(fmaxf(fmaxf(v0.x, v0.y), fmaxf(v0.z, v0.w)),
                     fmaxf(fmaxf(v1.x, v1.y), fmaxf(v1.z, v1.w)));
    #pragma unroll
    for (int off = 32; off; off >>= 1)
        mx = fmaxf(mx, __shfl_xor(mx, off));

    __shared__ float sm[4];
    __shared__ float ss[4];
    const int wid = tid >> 6, lane = tid & 63;
    if (lane == 0) sm[wid] = mx;
    __syncthreads();
    const float rmax = fmaxf(fmaxf(sm[0], sm[1]), fmaxf(sm[2], sm[3]));

    float e[8];
    e[0] = expf(v0.x - rmax); e[1] = expf(v0.y - rmax);
    e[2] = expf(v0.z - rmax); e[3] = expf(v0.w - rmax);
    e[4] = expf(v1.x - rmax); e[5] = expf(v1.y - rmax);
    e[6] = expf(v1.z - rmax); e[7] = expf(v1.w - rmax);

    float sum = 0.f;
    #pragma unroll
    for (int i = 0; i < 8; ++i) sum += e[i];
    #pragma unroll
    for (int off = 32; off; off >>= 1)
        sum += __shfl_xor(sum, off);
    if (lane == 0) ss[wid] = sum;
    __syncthreads();
    const float inv = 1.f / (ss[0] + ss[1] + ss[2] + ss[3]);

    float4 r0, r1;
    r0.x = e[0] * inv; r0.y = e[1] * inv; r0.z = e[2] * inv; r0.w = e[3] * inv;
    r1.x = e[4] * inv; r1.y = e[5] * inv; r1.z = e[6] * inv; r1.w = e[7] * inv;
    *(float4*)&p[tid * 4] = r0;
    *(float4*)&p[tid * 4 + 1024] = r1;
    ph[tid]       = (half4v){(half_t)r0.x, (half_t)r0.y, (half_t)r0.z, (half_t)r0.w};
    ph[tid + 256] = (half4v){(half_t)r1.x, (half_t)r1.y, (half_t)r1.z, (half_t)r1.w};
}

extern "C" void kernel_launch(void* const* d_in, const int* in_sizes, int n_in,
                              void* d_out, int out_size, void* d_ws, size_t ws_size,
                              hipStream_t stream) {
    const float* base = (const float*)d_in[0];  // [B,C,T,1]
    const float* x    = (const float*)d_in[1];  // [B,C,T,1]
    const float* top  = (const float*)d_in[2];  // [B,C,S]
    const float* comb = (const float*)d_in[3];  // [B,C,S]
    const float* W    = (const float*)d_in[4];  // [C,C]
    const float* bias = (const float*)d_in[5];  // [C]

    float* out    = (float*)d_out;
    float* ctx    = out;          // [B,C,T] final context output (f32)
    float* logits = out + BCT_;   // [B,T,S] logits -> attn output (f32)

    // fp16 staging in the ctx region of d_out (dead before K4 rewrites it):
    //   xT  [B][T][C] f16 (16.8MB) | topT [B][S][C] f16 (16.8MB)  = 33.55MB exact
    half_t* xT   = (half_t*)d_out;
    half_t* topT = xT + BCT_;     // BCT_ f16 elems = half the ctx region bytes

    // ws: attnh [B][T][S] f16 (67MB, tgtT aliases its head — dead before K3),
    //     combh [B][C][S] f16 (16.8MB), Wh [C][C] f16 (0.5MB). total 84.4MB.
    half_t* attnh = (half_t*)d_ws;
    half_t* tgtT  = attnh;                       // [B][T][C] f16, alias (see above)
    half_t* combh = attnh + BTS_;
    half_t* Wh    = combh + (size_t)B_ * C_ * S_;

    // converts / transposes
    transpose_cvt_kernel<<<dim3(T_ / 32, C_ / 32, B_), 256, 0, stream>>>(x, xT, C_, T_);
    transpose_cvt_kernel<<<dim3(S_ / 32, C_ / 32, B_), 256, 0, stream>>>(top, topT, C_, S_);
    cvt_f32_f16_kernel<<<2048, 256, 0, stream>>>(comb, combh, (int)((size_t)B_ * C_ * S_ / 4));
    cvt_f32_f16_kernel<<<256, 256, 0, stream>>>(W, Wh, C_ * C_ / 4);

    // K1: tgtT[b][t][o] = (x^T W^T + b + base)*SCALE   M=T,N=C,K=C, sB=0 (shared W)
    gemm_f16_kernel<1><<<dim3(C_ / 128, T_ / 128, B_), 256, 0, stream>>>(
        xT, Wh, nullptr, tgtT, base, bias,
        T_, C_, C_, (size_t)T_ * C_, 0, (size_t)T_ * C_);

    // K2: logits[b][t][s] = tgtT . topT                M=T,N=S,K=C
    gemm_f16_kernel<0><<<dim3(S_ / 128, T_ / 128, B_), 256, 0, stream>>>(
        tgtT, topT, logits, nullptr, nullptr, nullptr,
        T_, S_, C_, (size_t)T_ * C_, (size_t)S_ * C_, (size_t)T_ * S_);

    // K3: softmax rows, write f32 attn (output) + f16 attn (K4 operand)
    k3_softmax_kernel<<<dim3(B_ * T_), 256, 0, stream>>>(logits, attnh);

    // K4: ctx[b][c][t] = combh . attnh                 M=C,N=T,K=S
    gemm_f16_kernel<0><<<dim3(T_ / 128, C_ / 128, B_), 256, 0, stream>>>(
        combh, attnh, ctx, nullptr, nullptr, nullptr,
        C_, T_, S_, (size_t)C_ * S_, (size_t)T_ * S_, (size_t)C_ * T_);
}

// Round 3
// 212.001 us; speedup vs baseline: 4.9369x; 1.1639x over previous
//
#include <hip/hip_runtime.h>
#include <cstddef>
#include <cstdint>

#define SCALE_WEIGHT 0.70710678118654752440f

static constexpr int B_ = 8, C_ = 512, T_ = 2048, S_ = 2048;
static constexpr size_t BCT_ = (size_t)B_ * C_ * T_;   // 8.4M  (ctx region elems)
static constexpr size_t BTS_ = (size_t)B_ * T_ * S_;   // 33.5M (attn region elems)

typedef _Float16 half_t;
typedef half_t half8  __attribute__((ext_vector_type(8)));
typedef half_t half4v __attribute__((ext_vector_type(4)));
typedef float  floatx4 __attribute__((ext_vector_type(4)));

// async global->LDS, 16B per lane. LDS dest = wave-uniform base + lane*16.
__device__ __forceinline__ void gload_lds16(const void* g, void* l) {
    __builtin_amdgcn_global_load_lds(
        (const __attribute__((address_space(1))) void*)g,
        (__attribute__((address_space(3))) void*)l, 16, 0, 0);
}

// ---------------------------------------------------------------------------
// transpose+convert: in [b][R][Cc] f32 -> out [b][Cc][R] f16. 64x64 tiles,
// float4 global reads, half4 global writes, LDS stored pre-transposed.
// ---------------------------------------------------------------------------
__global__ __launch_bounds__(256) void transpose_cvt_kernel(
    const float* __restrict__ in, half_t* __restrict__ out, int R, int Cc)
{
    __shared__ float tile[64][65];   // tile[c_local][r_local]
    const int b  = blockIdx.z;
    const int r0 = blockIdx.y * 64, c0 = blockIdx.x * 64;
    const float* ib = in + (size_t)b * R * Cc;
    half_t* ob = out + (size_t)b * R * Cc;
    const int t  = threadIdx.x;
    const int rr = t >> 4, cq = t & 15;     // load: row rr+i*16, col quad cq*4
    #pragma unroll
    for (int i = 0; i < 4; ++i) {
        const int r = rr + i * 16;
        float4 v = *(const float4*)&ib[(size_t)(r0 + r) * Cc + c0 + cq * 4];
        tile[cq * 4 + 0][r] = v.x;
        tile[cq * 4 + 1][r] = v.y;
        tile[cq * 4 + 2][r] = v.z;
        tile[cq * 4 + 3][r] = v.w;
    }
    __syncthreads();
    const int cw = t >> 4, rq = (t & 15) * 4;  // store: col cw+i*16, rows rq..rq+3
    #pragma unroll
    for (int i = 0; i < 4; ++i) {
        const int c = cw + i * 16;
        half4v h = {(half_t)tile[c][rq + 0], (half_t)tile[c][rq + 1],
                    (half_t)tile[c][rq + 2], (half_t)tile[c][rq + 3]};
        *(half4v*)&ob[(size_t)(c0 + c) * R + r0 + rq] = h;
    }
}

// ---------------------------------------------------------------------------
// plain convert f32 -> f16 (same layout), float4-granular
// ---------------------------------------------------------------------------
__global__ __launch_bounds__(256) void cvt_f32_f16_kernel(
    const float* __restrict__ in, half_t* __restrict__ out, int n4)
{
    const int stride = gridDim.x * blockDim.x;
    for (int i = blockIdx.x * blockDim.x + threadIdx.x; i < n4; i += stride) {
        float4 v = ((const float4*)in)[i];
        half4v h = {(half_t)v.x, (half_t)v.y, (half_t)v.z, (half_t)v.w};
        ((half4v*)out)[i] = h;
    }
}

// ---------------------------------------------------------------------------
// MFMA fp16 GEMM: 128x128 tile, 4 waves (64x64 each), BK=64, double-buffered
// LDS, 2-phase pipeline with counted vmcnt(8) (T3-minimum recipe).
// LDS row = 64 halves = 128B = 8 slots of 16B; slot = kg ^ (row&7) swizzle
// (2 lanes/bank per 16-lane phase = conflict-free), inverse applied on the
// per-lane global source so global_load_lds' linear lane*16 write lands the
// swizzled content (both-sides involution).
// A: [M][K] f16 k-contig.  B: [N][K] f16 k-contig.  C: [M][N].
// EPI 0: f32 store.  EPI 1 (K1): f16 store of (acc + bias[n] + base[b][n][m])*SCALE.
// ---------------------------------------------------------------------------
template<int EPI>
__global__ __launch_bounds__(256) void gemm_f16_db_kernel(
    const half_t* __restrict__ A, const half_t* __restrict__ Bm,
    float* __restrict__ Cout, half_t* __restrict__ CoutH,
    const float* __restrict__ base, const float* __restrict__ bias,
    int M, int N, int K, size_t sA, size_t sB, size_t sC)
{
    __shared__ __align__(128) half_t As[2][128 * 64];
    __shared__ __align__(128) half_t Bs[2][128 * 64];

    const int tid  = threadIdx.x;
    const int lane = tid & 63, w = tid >> 6;
    const int wr = w >> 1, wc = w & 1;
    const int b  = blockIdx.z;
    const int m0 = blockIdx.y * 128, n0 = blockIdx.x * 128;

    const half_t* Ab = A  + (size_t)b * sA;
    const half_t* Bb = Bm + (size_t)b * sB;

    // ---- staging: wave w owns rows [w*32, w*32+32), 4 chunks of 8 rows ----
    const int lr = lane >> 3;            // row within chunk (0..7)
    const int sw = (lane & 7) ^ lr;      // swizzled source k-group (slot=lane&7)
    const half_t* aG[4]; const half_t* bG[4];
    int dOff[4];
    #pragma unroll
    for (int i = 0; i < 4; ++i) {
        const int r = w * 32 + i * 8 + lr;
        aG[i] = Ab + (size_t)(m0 + r) * K + sw * 8;
        bG[i] = Bb + (size_t)(n0 + r) * K + sw * 8;
        dOff[i] = (w * 32 + i * 8) * 128;   // LDS byte offset of chunk base
    }

    // ---- fragment ds_read byte offsets (kk=1 half is addr ^ 64) ----
    const int fr = lane & 15, kg = lane >> 4;
    int aoff[4], boff[4];
    #pragma unroll
    for (int mi = 0; mi < 4; ++mi) {
        const int m = wr * 64 + mi * 16 + fr;
        aoff[mi] = m * 128 + ((kg ^ (m & 7)) << 4);
    }
    #pragma unroll
    for (int nj = 0; nj < 4; ++nj) {
        const int n = wc * 64 + nj * 16 + fr;
        boff[nj] = n * 128 + ((kg ^ (n & 7)) << 4);
    }

    floatx4 acc[4][4];
    #pragma unroll
    for (int mi = 0; mi < 4; ++mi)
        #pragma unroll
        for (int nj = 0; nj < 4; ++nj)
            acc[mi][nj] = (floatx4){0.f, 0.f, 0.f, 0.f};

    auto STAGE = [&](int t, int pg) {
        const int k0 = t * 64;
        char* Ad = (char*)As[pg];
        char* Bd = (char*)Bs[pg];
        #pragma unroll
        for (int i = 0; i < 4; ++i) {
            gload_lds16(aG[i] + k0, Ad + dOff[i]);
            gload_lds16(bG[i] + k0, Bd + dOff[i]);
        }
    };

    auto COMPUTE = [&](int pg) {
        const char* Ar = (const char*)As[pg];
        const char* Br = (const char*)Bs[pg];
        #pragma unroll
        for (int kk = 0; kk < 2; ++kk) {
            half8 af[4], bf[4];
            #pragma unroll
            for (int mi = 0; mi < 4; ++mi)
                af[mi] = *(const half8*)(Ar + (aoff[mi] ^ (kk << 6)));
            #pragma unroll
            for (int nj = 0; nj < 4; ++nj)
                bf[nj] = *(const half8*)(Br + (boff[nj] ^ (kk << 6)));
            #pragma unroll
            for (int mi = 0; mi < 4; ++mi)
                #pragma unroll
                for (int nj = 0; nj < 4; ++nj)
                    acc[mi][nj] = __builtin_amdgcn_mfma_f32_16x16x32_f16(
                        af[mi], bf[nj], acc[mi][nj], 0, 0, 0);
        }
    };

    const int NT = K >> 6;               // K/64 tiles (>=2 for all our shapes)
    STAGE(0, 0);
    int cur = 0;
    for (int t = 0; t < NT - 1; ++t) {
        STAGE(t + 1, cur ^ 1);                         // 8 loads in flight
        asm volatile("s_waitcnt vmcnt(8)" ::: "memory"); // own tile-t loads done
        __builtin_amdgcn_s_barrier();                  // everyone's tile-t done
        __builtin_amdgcn_sched_barrier(0);             // no LDS-read hoist above
        COMPUTE(cur);
        asm volatile("s_waitcnt lgkmcnt(0)" ::: "memory"); // ds_reads complete
        __builtin_amdgcn_sched_barrier(0);
        __builtin_amdgcn_s_barrier();                  // buf[cur] free to overwrite
        __builtin_amdgcn_sched_barrier(0);
        cur ^= 1;
    }
    asm volatile("s_waitcnt vmcnt(0)" ::: "memory");
    __builtin_amdgcn_s_barrier();
    __builtin_amdgcn_sched_barrier(0);
    COMPUTE(cur);

    if constexpr (EPI == 0) {
        float* Cb = Cout + (size_t)b * sC;
        #pragma unroll
        for (int mi = 0; mi < 4; ++mi) {
            const int row = m0 + wr * 64 + mi * 16 + (lane >> 4) * 4;
            #pragma unroll
            for (int nj = 0; nj < 4; ++nj) {
                const int col = n0 + wc * 64 + nj * 16 + (lane & 15);
                #pragma unroll
                for (int r = 0; r < 4; ++r)
                    Cb[(size_t)(row + r) * N + col] = acc[mi][nj][r];
            }
        }
    } else {
        half_t* Cb = CoutH + (size_t)b * sC;
        #pragma unroll
        for (int nj = 0; nj < 4; ++nj) {
            const int col = n0 + wc * 64 + nj * 16 + (lane & 15);
            const float bn = bias[col];
            const float* bp = base + ((size_t)b * N + col) * (size_t)M;
            #pragma unroll
            for (int mi = 0; mi < 4; ++mi) {
                const int row = m0 + wr * 64 + mi * 16 + (lane >> 4) * 4;
                #pragma unroll
                for (int r = 0; r < 4; ++r) {
                    float v = (acc[mi][nj][r] + bn + bp[row + r]) * SCALE_WEIGHT;
                    Cb[(size_t)(row + r) * N + col] = (half_t)v;
                }
            }
        }
    }
}

// ---------------------------------------------------------------------------
// row softmax over S, in-place f32 + fp16 copy for the K4 MFMA operand
// ---------------------------------------------------------------------------
__global__ __launch_bounds__(256) void k3_softmax_kernel(
    float* __restrict__ logits, half_t* __restrict__ attnh)
{
    float* p = logits + (size_t)blockIdx.x * S_;
    half4v* ph = (half4v*)(attnh + (size_t)blockIdx.x * S_);
    const int tid = threadIdx.x;
    float4 v0 = *(const float4*)&p[tid * 4];
    float4 v1 = *(const float4*)&p[tid * 4 + 1024];

    float mx = fmaxf(fmaxf(fmaxf(v0.x, v0.y), fmaxf(v0.z, v0.w)),
                     fmaxf(fmaxf(v1.x, v1.y), fmaxf(v1.z, v1.w)));
    #pragma unroll
    for (int off = 32; off; off >>= 1)
        mx = fmaxf(mx, __shfl_xor(mx, off));

    __shared__ float sm[4];
    __shared__ float ss[4];
    const int wid = tid >> 6, lane = tid & 63;
    if (lane == 0) sm[wid] = mx;
    __syncthreads();
    const float rmax = fmaxf(fmaxf(sm[0], sm[1]), fmaxf(sm[2], sm[3]));

    float e[8];
    e[0] = __expf(v0.x - rmax); e[1] = __expf(v0.y - rmax);
    e[2] = __expf(v0.z - rmax); e[3] = __expf(v0.w - rmax);
    e[4] = __expf(v1.x - rmax); e[5] = __expf(v1.y - rmax);
    e[6] = __expf(v1.z - rmax); e[7] = __expf(v1.w - rmax);

    float sum = 0.f;
    #pragma unroll
    for (int i = 0; i < 8; ++i) sum += e[i];
    #pragma unroll
    for (int off = 32; off; off >>= 1)
        sum += __shfl_xor(sum, off);
    if (lane == 0) ss[wid] = sum;
    __syncthreads();
    const float inv = 1.f / (ss[0] + ss[1] + ss[2] + ss[3]);

    float4 r0, r1;
    r0.x = e[0] * inv; r0.y = e[1] * inv; r0.z = e[2] * inv; r0.w = e[3] * inv;
    r1.x = e[4] * inv; r1.y = e[5] * inv; r1.z = e[6] * inv; r1.w = e[7] * inv;
    *(float4*)&p[tid * 4] = r0;
    *(float4*)&p[tid * 4 + 1024] = r1;
    ph[tid]       = (half4v){(half_t)r0.x, (half_t)r0.y, (half_t)r0.z, (half_t)r0.w};
    ph[tid + 256] = (half4v){(half_t)r1.x, (half_t)r1.y, (half_t)r1.z, (half_t)r1.w};
}

extern "C" void kernel_launch(void* const* d_in, const int* in_sizes, int n_in,
                              void* d_out, int out_size, void* d_ws, size_t ws_size,
                              hipStream_t stream) {
    const float* base = (const float*)d_in[0];  // [B,C,T,1]
    const float* x    = (const float*)d_in[1];  // [B,C,T,1]
    const float* top  = (const float*)d_in[2];  // [B,C,S]
    const float* comb = (const float*)d_in[3];  // [B,C,S]
    const float* W    = (const float*)d_in[4];  // [C,C]
    const float* bias = (const float*)d_in[5];  // [C]

    float* out    = (float*)d_out;
    float* ctx    = out;          // [B,C,T] final context output (f32)
    float* logits = out + BCT_;   // [B,T,S] logits -> attn output (f32)

    // fp16 staging in the ctx region of d_out (dead before K4 rewrites it):
    //   xT  [B][T][C] f16 (16.8MB) | topT [B][S][C] f16 (16.8MB)  = 33.55MB exact
    half_t* xT   = (half_t*)d_out;
    half_t* topT = xT + BCT_;     // BCT_ f16 elems = half the ctx region bytes

    // ws: attnh [B][T][S] f16 (67MB, tgtT aliases its head — dead before K3),
    //     combh [B][C][S] f16 (16.8MB), Wh [C][C] f16 (0.5MB). total 84.4MB.
    half_t* attnh = (half_t*)d_ws;
    half_t* tgtT  = attnh;                       // [B][T][C] f16, alias (see above)
    half_t* combh = attnh + BTS_;
    half_t* Wh    = combh + (size_t)B_ * C_ * S_;

    // converts / transposes
    transpose_cvt_kernel<<<dim3(T_ / 64, C_ / 64, B_), 256, 0, stream>>>(x, xT, C_, T_);
    transpose_cvt_kernel<<<dim3(S_ / 64, C_ / 64, B_), 256, 0, stream>>>(top, topT, C_, S_);
    cvt_f32_f16_kernel<<<2048, 256, 0, stream>>>(comb, combh, (int)((size_t)B_ * C_ * S_ / 4));
    cvt_f32_f16_kernel<<<256, 256, 0, stream>>>(W, Wh, C_ * C_ / 4);

    // K1: tgtT[b][t][o] = (x^T W^T + b + base)*SCALE   M=T,N=C,K=C, sB=0 (shared W)
    gemm_f16_db_kernel<1><<<dim3(C_ / 128, T_ / 128, B_), 256, 0, stream>>>(
        xT, Wh, nullptr, tgtT, base, bias,
        T_, C_, C_, (size_t)T_ * C_, 0, (size_t)T_ * C_);

    // K2: logits[b][t][s] = tgtT . topT                M=T,N=S,K=C
    gemm_f16_db_kernel<0><<<dim3(S_ / 128, T_ / 128, B_), 256, 0, stream>>>(
        tgtT, topT, logits, nullptr, nullptr, nullptr,
        T_, S_, C_, (size_t)T_ * C_, (size_t)S_ * C_, (size_t)T_ * S_);

    // K3: softmax rows, write f32 attn (output) + f16 attn (K4 operand)
    k3_softmax_kernel<<<dim3(B_ * T_), 256, 0, stream>>>(logits, attnh);

    // K4: ctx[b][c][t] = combh . attnh                 M=C,N=T,K=S
    gemm_f16_db_kernel<0><<<dim3(T_ / 128, C_ / 128, B_), 256, 0, stream>>>(
        combh, attnh, ctx, nullptr, nullptr, nullptr,
        C_, T_, S_, (size_t)C_ * S_, (size_t)T_ * S_, (size_t)C_ * T_);
}